// Round 9
// baseline (558.519 us; speedup 1.0000x reference)
//
#include <hip/hip_runtime.h>
#include <hip/hip_cooperative_groups.h>

namespace cg = cooperative_groups;

// GCN layer: out = sum_r segment_sum(vals_r * inp[src_r], dst_r) @ W_r
// Round 9: ONE cooperative dispatch, phases separated by grid.sync():
//   A) inp->bf16, W->Wt[r][n][k] bf16, zero counts.
//   B) hist: counts[seg]++ for seg=rel*N+dst (400K ctrs, ~2/ctr).
//   C) scan: c1 per-tile partial sums; c2 per-tile base (reduce partials)
//      + block scan + write offs. offs[S] = R*E analytically.
//   D) fill: csr[offs[seg] + countdown(counts[seg])] = {src,val}.
//   E) fused: tile = 64 dst rows x 128 cols. Per relation: gather agg rows
//      from CSR into LDS (4 thr/row, unroll-2 edge loop, f32->bf16 pack),
//      MFMA 16x16x32 bf16, acc in regs across relations, out f32 once.
// N=50000, R=8, E=100000, IN=OUT=128.

constexpr int IN    = 128;
constexpr int OUT   = 128;
constexpr int BROWS = 64;    // dst rows per fused tile
constexpr int LDK   = 136;   // padded LDS row (bf16) = 272 B (16B-aligned)
constexpr int NT    = 1024;  // scan tiles

typedef __attribute__((ext_vector_type(8))) short bf16x8;
typedef __attribute__((ext_vector_type(4))) float f32x4;

__device__ inline unsigned short f2bf(float f) {
    unsigned int u = __float_as_uint(f);
    u += 0x7fffu + ((u >> 16) & 1u);          // RNE
    return (unsigned short)(u >> 16);
}
__device__ inline unsigned pack2(float a, float b) {
    return (unsigned)f2bf(a) | ((unsigned)f2bf(b) << 16);
}
__device__ inline float bflo(unsigned int u) { return __uint_as_float(u << 16); }
__device__ inline float bfhi(unsigned int u) { return __uint_as_float(u & 0xffff0000u); }

__global__ __launch_bounds__(256, 4) void mega_kernel(
    const float* __restrict__ inp, const float* __restrict__ w,
    const int* __restrict__ src, const int* __restrict__ dst,
    const float* __restrict__ vals,
    unsigned short* __restrict__ inpb, unsigned short* __restrict__ wt,
    int* __restrict__ counts, int* __restrict__ partials,
    int* __restrict__ offs, int2* __restrict__ csr,
    float* __restrict__ out,
    int n_nodes, int n_rel, int n_edges)
{
    cg::grid_group gg = cg::this_grid();
    const int tid = threadIdx.x;
    const int gtid = blockIdx.x * 256 + tid;
    const int gstride = gridDim.x * 256;
    const int S = n_rel * n_nodes;

    __shared__ __align__(16) char shraw[BROWS * LDK * 2];   // 17.4 KB union
    int* ps = (int*)shraw;                                  // [256] scan temp
    unsigned short* As = (unsigned short*)shraw;            // fused A-tile

    // ---------------- A: converts + zero ----------------
    {
        const int n8 = n_nodes * (IN / 8);
        for (int i = gtid; i < n8; i += gstride) {
            const float4 a = ((const float4*)inp)[i * 2];
            const float4 c = ((const float4*)inp)[i * 2 + 1];
            uint4 o;
            o.x = pack2(a.x, a.y);  o.y = pack2(a.z, a.w);
            o.z = pack2(c.x, c.y);  o.w = pack2(c.z, c.w);
            ((uint4*)inpb)[i] = o;
        }
        const int wt_tot = n_rel * IN * OUT;
        for (int t = gtid; t < wt_tot; t += gstride) {
            const int r = t >> 14, rem = t & 16383;
            const int n = rem >> 7, k = rem & 127;
            wt[t] = f2bf(w[(r << 14) + (k << 7) + n]);       // Wt[r][n][k]
        }
        for (int i = gtid; i < S; i += gstride) counts[i] = 0;
    }
    gg.sync();

    // ---------------- B: histogram ----------------
    for (int r = 0; r < n_rel; ++r) {
        const int* dr = dst + (size_t)r * n_edges;
        const int base = r * n_nodes;
        for (int e = gtid; e < n_edges; e += gstride)
            atomicAdd(&counts[base + dr[e]], 1);
    }
    gg.sync();

    // ---------------- C1: per-tile partial sums ----------------
    const int T   = (S + NT - 1) / NT;          // elems per tile
    const int npt = (T + 255) / 256;            // elems per thread (<=8)
    for (int tile = blockIdx.x; tile < NT; tile += gridDim.x) {
        const int tb = tile * T;
        int s = 0;
        for (int i = 0; i < npt; ++i) {
            const int idx = tb + tid * npt + i;
            if (idx < tb + T && idx < S) s += counts[idx];
        }
        ps[tid] = s;
        __syncthreads();
        #pragma unroll
        for (int d = 128; d > 0; d >>= 1) {
            if (tid < d) ps[tid] += ps[tid + d];
            __syncthreads();
        }
        if (tid == 0) partials[tile] = ps[0];
        __syncthreads();
    }
    gg.sync();

    // ---------------- C2: base + block scan -> offs ----------------
    for (int tile = blockIdx.x; tile < NT; tile += gridDim.x) {
        // base = sum partials[0..tile)
        int p = 0;
        for (int i = tid; i < tile; i += 256) p += partials[i];
        ps[tid] = p;
        __syncthreads();
        #pragma unroll
        for (int d = 128; d > 0; d >>= 1) {
            if (tid < d) ps[tid] += ps[tid + d];
            __syncthreads();
        }
        const int base = ps[0];
        __syncthreads();

        const int tb = tile * T;
        int c[8];
        int s = 0;
        for (int i = 0; i < npt; ++i) {
            const int idx = tb + tid * npt + i;
            c[i] = (idx < tb + T && idx < S) ? counts[idx] : 0;
            s += c[i];
        }
        ps[tid] = s;
        __syncthreads();
        #pragma unroll
        for (int d = 1; d < 256; d <<= 1) {
            const int v = (tid >= d) ? ps[tid - d] : 0;
            __syncthreads();
            ps[tid] += v;
            __syncthreads();
        }
        int excl = base + ps[tid] - s;
        for (int i = 0; i < npt; ++i) {
            const int idx = tb + tid * npt + i;
            if (idx < tb + T && idx < S) offs[idx] = excl;
            excl += c[i];
        }
        __syncthreads();
    }
    if (gtid == 0) offs[S] = n_rel * n_edges;   // grand total, analytically
    gg.sync();

    // ---------------- D: fill (countdown; counts -> 0) ----------------
    for (int r = 0; r < n_rel; ++r) {
        const int* sr = src + (size_t)r * n_edges;
        const int* dr = dst + (size_t)r * n_edges;
        const float* vr = vals + (size_t)r * n_edges;
        const int base = r * n_nodes;
        for (int e = gtid; e < n_edges; e += gstride) {
            const int seg = base + dr[e];
            const int idx = atomicAdd(&counts[seg], -1) - 1;
            csr[offs[seg] + idx] = make_int2(sr[e], __float_as_int(vr[e]));
        }
    }
    gg.sync();

    // ---------------- E: fused aggregate + GEMM ----------------
    const int ntiles = (n_nodes + BROWS - 1) / BROWS;
    const int wave = tid >> 6, lane = tid & 63;
    const int m = lane & 15, q = lane >> 4;
    const int srow = tid >> 2, qt = tid & 3;     // staging: 4 thr/row, 32 cols

    for (int bkt = blockIdx.x; bkt < ntiles; bkt += gridDim.x) {
        const int row0 = bkt * BROWS;

        f32x4 acc[4][2];
        #pragma unroll
        for (int mt = 0; mt < 4; ++mt)
            #pragma unroll
            for (int nt = 0; nt < 2; ++nt)
                acc[mt][nt] = (f32x4){0.f, 0.f, 0.f, 0.f};

        for (int r = 0; r < n_rel; ++r) {
            __syncthreads();   // As reuse

            float accs[32];
            #pragma unroll
            for (int i = 0; i < 32; ++i) accs[i] = 0.f;
            const int grow = row0 + srow;
            if (grow < n_nodes) {
                const int seg = r * n_nodes + grow;
                const int b = offs[seg], e = offs[seg + 1];
                int j = b;
                for (; j + 2 <= e; j += 2) {     // 2 edges in flight
                    const int2 r0 = csr[j], r1 = csr[j + 1];
                    const float v0 = __int_as_float(r0.y);
                    const float v1 = __int_as_float(r1.y);
                    const uint4* g0 = (const uint4*)(
                        inpb + (size_t)r0.x * IN + qt * 32);
                    const uint4* g1 = (const uint4*)(
                        inpb + (size_t)r1.x * IN + qt * 32);
                    #pragma unroll
                    for (int w4 = 0; w4 < 4; ++w4) {
                        const uint4 u0 = g0[w4], u1 = g1[w4];
                        accs[w4*8+0] += v0*bflo(u0.x) + v1*bflo(u1.x);
                        accs[w4*8+1] += v0*bfhi(u0.x) + v1*bfhi(u1.x);
                        accs[w4*8+2] += v0*bflo(u0.y) + v1*bflo(u1.y);
                        accs[w4*8+3] += v0*bfhi(u0.y) + v1*bfhi(u1.y);
                        accs[w4*8+4] += v0*bflo(u0.z) + v1*bflo(u1.z);
                        accs[w4*8+5] += v0*bfhi(u0.z) + v1*bfhi(u1.z);
                        accs[w4*8+6] += v0*bflo(u0.w) + v1*bflo(u1.w);
                        accs[w4*8+7] += v0*bfhi(u0.w) + v1*bfhi(u1.w);
                    }
                }
                if (j < e) {
                    const int2 r0 = csr[j];
                    const float v0 = __int_as_float(r0.y);
                    const uint4* g0 = (const uint4*)(
                        inpb + (size_t)r0.x * IN + qt * 32);
                    #pragma unroll
                    for (int w4 = 0; w4 < 4; ++w4) {
                        const uint4 u0 = g0[w4];
                        accs[w4*8+0] += v0*bflo(u0.x);
                        accs[w4*8+1] += v0*bfhi(u0.x);
                        accs[w4*8+2] += v0*bflo(u0.y);
                        accs[w4*8+3] += v0*bfhi(u0.y);
                        accs[w4*8+4] += v0*bflo(u0.z);
                        accs[w4*8+5] += v0*bfhi(u0.z);
                        accs[w4*8+6] += v0*bflo(u0.w);
                        accs[w4*8+7] += v0*bfhi(u0.w);
                    }
                }
            }
            {   // pack bf16, 16B LDS stores (row stride 272 B = 17x16)
                uint4* lp4 = (uint4*)&As[srow * LDK + qt * 32];
                #pragma unroll
                for (int w4 = 0; w4 < 4; ++w4)
                    lp4[w4] = make_uint4(
                        pack2(accs[w4*8+0], accs[w4*8+1]),
                        pack2(accs[w4*8+2], accs[w4*8+3]),
                        pack2(accs[w4*8+4], accs[w4*8+5]),
                        pack2(accs[w4*8+6], accs[w4*8+7]));
            }

            bf16x8 bfrag[2][4];   // B fragments (L2-hot wt)
            {
                const unsigned short* wtr =
                    wt + ((size_t)r * OUT + wave * 32) * IN;
                #pragma unroll
                for (int nt = 0; nt < 2; ++nt)
                    #pragma unroll
                    for (int ks = 0; ks < 4; ++ks)
                        bfrag[nt][ks] = *(const bf16x8*)(
                            wtr + (size_t)(nt * 16 + m) * IN + ks * 32 + q * 8);
            }
            __syncthreads();

            #pragma unroll
            for (int ks = 0; ks < 4; ++ks) {
                bf16x8 a[4];
                #pragma unroll
                for (int mt = 0; mt < 4; ++mt)
                    a[mt] = *(const bf16x8*)
                        &As[(mt * 16 + m) * LDK + ks * 32 + q * 8];
                #pragma unroll
                for (int mt = 0; mt < 4; ++mt) {
                    acc[mt][0] = __builtin_amdgcn_mfma_f32_16x16x32_bf16(
                        a[mt], bfrag[0][ks], acc[mt][0], 0, 0, 0);
                    acc[mt][1] = __builtin_amdgcn_mfma_f32_16x16x32_bf16(
                        a[mt], bfrag[1][ks], acc[mt][1], 0, 0, 0);
                }
            }
        }

        // store: C/D lane holds rows q*4+0..3, col = nt*16 + m
        #pragma unroll
        for (int mt = 0; mt < 4; ++mt) {
            #pragma unroll
            for (int rg = 0; rg < 4; ++rg) {
                const int row = row0 + mt * 16 + q * 4 + rg;
                if (row < n_nodes) {
                    float* op = out + (size_t)row * OUT + wave * 32 + m;
                    op[0]  = acc[mt][0][rg];
                    op[16] = acc[mt][1][rg];
                }
            }
        }
        __syncthreads();   // As protected before next tile
    }
}

// ---------------- fallback: per-edge GEMV scatter (no ws / no coop) ---------
__global__ __launch_bounds__(256) void gemv_scatter_kernel(
    const float* __restrict__ inp, const float* __restrict__ weights,
    const int* __restrict__ src, const int* __restrict__ dst,
    const float* __restrict__ vals, float* __restrict__ out, int n_edges)
{
    const int e = blockIdx.x * 4 + (threadIdx.x >> 6);
    if (e >= n_edges) return;
    const int lane = threadIdx.x & 63;
    const int r = blockIdx.y;
    const size_t g = (size_t)r * n_edges + e;
    const int s = src[g], d = dst[g];
    const float v = vals[g];
    const float* __restrict__ arow = inp + (size_t)s * IN;
    const float* __restrict__ W = weights + (size_t)r * IN * OUT;
    float a0 = 0.f, a1 = 0.f;
    for (int k = 0; k < IN; ++k) {
        const float av = arow[k];
        a0 = fmaf(av, W[k * OUT + lane], a0);
        a1 = fmaf(av, W[k * OUT + lane + 64], a1);
    }
    float* orow = out + (size_t)d * OUT;
    __hip_atomic_fetch_add(orow + lane, v * a0, __ATOMIC_RELAXED,
                           __HIP_MEMORY_SCOPE_AGENT);
    __hip_atomic_fetch_add(orow + lane + 64, v * a1, __ATOMIC_RELAXED,
                           __HIP_MEMORY_SCOPE_AGENT);
}

extern "C" void kernel_launch(void* const* d_in, const int* in_sizes, int n_in,
                              void* d_out, int out_size, void* d_ws, size_t ws_size,
                              hipStream_t stream) {
    const float* inp     = (const float*)d_in[0];
    const int*   src     = (const int*)  d_in[1];
    const int*   dst     = (const int*)  d_in[2];
    const float* vals    = (const float*)d_in[3];
    const float* weights = (const float*)d_in[4];
    float* out = (float*)d_out;

    const int n_nodes = in_sizes[0] / IN;            // 50000
    const int n_rel   = in_sizes[4] / (IN * OUT);    // 8
    const int n_edges = in_sizes[1] / n_rel;         // 100000
    const int total_edges = n_rel * n_edges;
    const int S = n_rel * n_nodes;

    auto align_up = [](size_t x) { return (x + 255) & ~(size_t)255; };
    const size_t sz_inpb = align_up((size_t)n_nodes * IN * 2);
    const size_t sz_wt   = align_up((size_t)n_rel * IN * OUT * 2);
    const size_t sz_cnt  = align_up((size_t)S * 4);
    const size_t sz_part = align_up((size_t)NT * 4);
    const size_t sz_offs = align_up((size_t)(S + 1) * 4);
    const size_t sz_csr  = align_up((size_t)total_edges * 8);
    const size_t need = sz_inpb + sz_wt + sz_cnt + sz_part + sz_offs + sz_csr;

    bool launched = false;
    if (need <= ws_size && (size_t)S + 1 <= (size_t)NT * 2048) {
        char* p = (char*)d_ws;
        unsigned short* inpb = (unsigned short*)p;  p += sz_inpb;
        unsigned short* wtb  = (unsigned short*)p;  p += sz_wt;
        int* counts   = (int*)p;   p += sz_cnt;
        int* partials = (int*)p;   p += sz_part;
        int* offs     = (int*)p;   p += sz_offs;
        int2* csr     = (int2*)p;

        int blocksPerCU = 0;
        hipError_t oerr = hipOccupancyMaxActiveBlocksPerMultiprocessor(
            &blocksPerCU, mega_kernel, 256, 0);
        if (oerr == hipSuccess && blocksPerCU > 0) {
            hipDeviceProp_t props;
            int dev = 0;
            hipGetDevice(&dev);
            if (hipGetDeviceProperties(&props, dev) == hipSuccess) {
                long long grid = (long long)blocksPerCU *
                                 props.multiProcessorCount;
                if (grid > 2048) grid = 2048;
                if (grid >= 64) {
                    int gi = (int)grid;
                    void* args[] = {
                        (void*)&inp, (void*)&weights, (void*)&src, (void*)&dst,
                        (void*)&vals, (void*)&inpb, (void*)&wtb, (void*)&counts,
                        (void*)&partials, (void*)&offs, (void*)&csr, (void*)&out,
                        (void*)&n_nodes, (void*)&n_rel, (void*)&n_edges };
                    hipError_t lerr = hipLaunchCooperativeKernel(
                        (const void*)mega_kernel, dim3(gi), dim3(256),
                        args, 0, stream);
                    launched = (lerr == hipSuccess);
                }
            }
        }
    }

    if (!launched) {
        // slow-but-correct fallback
        hipMemsetAsync(out, 0, (size_t)n_nodes * OUT * 4, stream);
        dim3 g((n_edges + 3) / 4, n_rel);
        gemv_scatter_kernel<<<g, 256, 0, stream>>>(inp, weights, src, dst,
                                                   vals, out, n_edges);
    }
}